// Round 10
// baseline (159.080 us; speedup 1.0000x reference)
//
#include <hip/hip_runtime.h>

#define H 2048
#define MDIM 512
#define NE 8
#define MS 1024
#define NTOK 2048
#define ACT_R_ROWS 5120

typedef unsigned short u16;
typedef __attribute__((ext_vector_type(4))) short s16x4;
typedef __attribute__((ext_vector_type(8))) short s16x8;
typedef __attribute__((ext_vector_type(4))) float f32x4;

__device__ inline u16 f2bf(float f) {
  unsigned u = __builtin_bit_cast(unsigned, f);
  u = (u + 0x7fffu + ((u >> 16) & 1u)) >> 16;
  return (u16)u;
}
__device__ inline float bf2f(u16 v) {
  return __builtin_bit_cast(float, (unsigned)v << 16);
}

__device__ inline f32x4 mfma16(s16x8 a, s16x8 b, f32x4 c) {
  return __builtin_amdgcn_mfma_f32_16x16x32_bf16(a, b, c, 0, 0, 0);
}

// async global->LDS, 16B per lane. LDS dest wave-uniform base (+lane*16).
__device__ inline void gload16(const void* g, void* l) {
  __builtin_amdgcn_global_load_lds(
      (const __attribute__((address_space(1))) unsigned int*)g,
      (__attribute__((address_space(3))) unsigned int*)l, 16, 0, 0);
}

// ---------------- merged front: x-convert+router logits (blocks 0..511)
// ---------------- + all 6 weight transposes (blocks 512..8191) ----------------

__device__ inline void tile_t64(const float* __restrict__ src, u16* __restrict__ dst,
                                int R, int C, int bx, int by, u16 (*tt)[66]) {
  int c0 = bx * 64, r0 = by * 64;
  int t = threadIdx.x;
  int cq = (t & 15) * 4, rr = t >> 4;
  #pragma unroll
  for (int i = 0; i < 4; i++) {
    int row = rr + i * 16;
    f32x4 v = *(const f32x4*)&src[(long)(r0 + row) * C + c0 + cq];
    tt[cq + 0][row] = f2bf(v[0]);
    tt[cq + 1][row] = f2bf(v[1]);
    tt[cq + 2][row] = f2bf(v[2]);
    tt[cq + 3][row] = f2bf(v[3]);
  }
  __syncthreads();
  int c = t >> 2, ch = t & 3;
  #pragma unroll
  for (int h = 0; h < 2; h++) {
    int chunk = ch + h * 4;
    const u16* p = &tt[c][chunk * 8];
    s16x8 o;
    #pragma unroll
    for (int w0 = 0; w0 < 8; w0++) o[w0] = (short)p[w0];
    *(s16x8*)&dst[(long)(c0 + c) * R + r0 + chunk * 8] = o;
  }
}

__global__ __launch_bounds__(256) void k_front(
    const float* __restrict__ x, const float* __restrict__ gw,
    u16* __restrict__ xbf, int* __restrict__ te, float* __restrict__ tw,
    const float* __restrict__ Wg, const float* __restrict__ Wu,
    const float* __restrict__ Wd, const float* __restrict__ sWg,
    const float* __restrict__ sWu, const float* __restrict__ sWd,
    u16* __restrict__ WgT, u16* __restrict__ WuT, u16* __restrict__ WdT,
    u16* __restrict__ sWgT, u16* __restrict__ sWuT, u16* __restrict__ sWdT) {
  __shared__ u16 tt[64][66];
  int blk = blockIdx.x;
  if (blk < NTOK / 4) {
    // ---- xlog: fused x->bf16 convert + fp64 router logits + top-2 ----
    int n = blk * 4 + (threadIdx.x >> 6);
    int lane = threadIdx.x & 63;
    double acc[NE];
    #pragma unroll
    for (int e = 0; e < NE; e++) acc[e] = 0.0;
    const f32x4* xr = (const f32x4*)(x + (size_t)n * H);
    s16x4* xo = (s16x4*)(xbf + (size_t)n * H);
    #pragma unroll
    for (int it = 0; it < H / 256; it++) {
      int j4 = it * 64 + lane;
      f32x4 v = xr[j4];
      s16x4 o;
      o[0] = (short)f2bf(v[0]); o[1] = (short)f2bf(v[1]);
      o[2] = (short)f2bf(v[2]); o[3] = (short)f2bf(v[3]);
      xo[j4] = o;
      #pragma unroll
      for (int e = 0; e < NE; e++) {
        f32x4 g = *(const f32x4*)&gw[e * H + j4 * 4];
        acc[e] += (double)v[0] * g[0] + (double)v[1] * g[1] +
                  (double)v[2] * g[2] + (double)v[3] * g[3];
      }
    }
    #pragma unroll
    for (int off = 32; off; off >>= 1) {
      #pragma unroll
      for (int e = 0; e < NE; e++) acc[e] += __shfl_xor(acc[e], off);
    }
    if (lane == 0) {
      int b0 = 0; double v0 = acc[0];
      #pragma unroll
      for (int e = 1; e < NE; e++) { if (acc[e] > v0) { v0 = acc[e]; b0 = e; } }
      int b1 = -1; double v1 = -1e300;
      #pragma unroll
      for (int e = 0; e < NE; e++) { if (e != b0 && acc[e] > v1) { v1 = acc[e]; b1 = e; } }
      double ex = exp(v1 - v0);
      te[n * 2] = b0; te[n * 2 + 1] = b1;
      tw[n * 2] = (float)(1.0 / (1.0 + ex));
      tw[n * 2 + 1] = (float)(ex / (1.0 + ex));
    }
    return;
  }
  // ---- weight transpose+convert ----
  int b = blk - NTOK / 4;
  const float* src; u16* dst; int R, C, lb;
  if (b < 2048) {
    lb = b; R = H; C = MDIM;
    int z = lb >> 8; lb &= 255;
    src = Wg + (size_t)z * H * MDIM; dst = WgT + (size_t)z * MDIM * H;
  } else if (b < 4096) {
    lb = b - 2048; R = H; C = MDIM;
    int z = lb >> 8; lb &= 255;
    src = Wu + (size_t)z * H * MDIM; dst = WuT + (size_t)z * MDIM * H;
  } else if (b < 6144) {
    lb = b - 4096; R = MDIM; C = H;
    int z = lb >> 8; lb &= 255;
    src = Wd + (size_t)z * MDIM * H; dst = WdT + (size_t)z * H * MDIM;
  } else if (b < 6656) {
    lb = b - 6144; R = H; C = MS; src = sWg; dst = sWgT;
  } else if (b < 7168) {
    lb = b - 6656; R = H; C = MS; src = sWu; dst = sWuT;
  } else {
    lb = b - 7168; R = MS; C = H; src = sWd; dst = sWdT;
  }
  int nbx = C >> 6;
  tile_t64(src, dst, R, C, lb % nbx, lb / nbx, tt);
}

// single-block deterministic dispatch build (no atomics)
__global__ __launch_bounds__(256) void k_build(
    const int* __restrict__ te, const float* __restrict__ tw,
    int* __restrict__ counts, int* __restrict__ offs,
    int* __restrict__ perm, float* __restrict__ wgt, int* __restrict__ slotmap) {
  __shared__ int cnt[256][NE];
  __shared__ int pb[NE];
  int t = threadIdx.x;
  int ebuf[16];
  int lc[NE];
  #pragma unroll
  for (int e = 0; e < NE; e++) lc[e] = 0;
  #pragma unroll
  for (int i = 0; i < 16; i++) {
    int ei = te[t * 16 + i];
    ebuf[i] = ei;
    #pragma unroll
    for (int e = 0; e < NE; e++) lc[e] += (ei == e) ? 1 : 0;
  }
  #pragma unroll
  for (int e = 0; e < NE; e++) cnt[t][e] = lc[e];
  __syncthreads();
  if (t < NE) {
    int run = 0;
    for (int i = 0; i < 256; i++) { int v = cnt[i][t]; cnt[i][t] = run; run += v; }
    counts[t] = run;
  }
  __syncthreads();
  if (t == 0) {
    int off = 0;
    #pragma unroll
    for (int e = 0; e < NE; e++) {
      pb[e] = off; offs[e] = off;
      off += ((counts[e] + 127) >> 7) << 7;
    }
    offs[NE] = off;
  }
  for (int i = t; i < ACT_R_ROWS; i += 256) { perm[i] = 0; wgt[i] = 0.f; }
  __syncthreads();
  int run2[NE];
  #pragma unroll
  for (int e = 0; e < NE; e++) run2[e] = cnt[t][e];
  #pragma unroll
  for (int i = 0; i < 16; i++) {
    int ei = ebuf[i];
    int idx = 0;
    #pragma unroll
    for (int e = 0; e < NE; e++) {
      if (ei == e) idx = pb[e] + run2[e];
      run2[e] += (ei == e) ? 1 : 0;
    }
    perm[idx] = (t * 16 + i) >> 1;
    wgt[idx] = tw[t * 16 + i];
    slotmap[t * 16 + i] = idx;
  }
}

// ---------------- fused gate+up+SwiGLU GEMM, 4-buffer ring, BK=32 ----------------
// C tile 128 rows x 64 cols. Groups: g<16 shared; else routed e=(g-16)>>3.
// Grid 1-D 1280 = 80 groups x 16 bx, XCD-grouped.
// LDS buffer 16KB (A 8K @0, Bg 4K @8K, Bu 4K @12K), ring of 4 = 64KB.
// Depth-3 prefetch: STAGE(t+3) issued at iter t -> ~3 iters (~1000cyc) to land,
// covering HBM miss latency (~900cyc). One barrier per iteration.
// Swizzle (64B rows, 4 chunks): chunk ^= (row>>1)&3  (8 distinct bank slots/8 rows).
__global__ __launch_bounds__(256, 2) void k_gu(
    const u16* __restrict__ xbf, const u16* __restrict__ WgT, const u16* __restrict__ WuT,
    const u16* __restrict__ sWgT, const u16* __restrict__ sWuT,
    u16* __restrict__ act_s, u16* __restrict__ act_r,
    const int* __restrict__ perm, const int* __restrict__ counts,
    const int* __restrict__ offs) {
  int lin = blockIdx.x;
  int xcd = lin & 7, jj = lin >> 3;
  int g = xcd + 8 * (jj % 10);   // 80 groups
  int bx = jj / 10;              // 16 row tiles
  const u16 *Bg, *Bu;
  u16* act;
  int Nout, cnt, rowBase, by;
  bool gather;
  if (g < 16) {
    gather = false; by = g;
    cnt = NTOK; rowBase = bx * 128;
    Bg = sWgT + (size_t)by * 64 * H;
    Bu = sWuT + (size_t)by * 64 * H;
    act = act_s; Nout = MS;
  } else {
    gather = true;
    int e = (g - 16) >> 3; by = (g - 16) & 7;
    cnt = counts[e];
    if (bx * 128 >= cnt) return;
    rowBase = offs[e] + bx * 128;
    Bg = WgT + ((size_t)e * MDIM + (size_t)by * 64) * H;
    Bu = WuT + ((size_t)e * MDIM + (size_t)by * 64) * H;
    act = act_r; Nout = MDIM;
  }

  __shared__ char lds[4][16384];

  int tid = threadIdx.x;
  int wave = tid >> 6, lane = tid & 63;
  int wr = wave >> 1, wc = wave & 1;
  int la = lane & 15, ks = lane >> 4;

  // staging global sources (pre-swizzled chunk within each 64B k-row)
  const char* srcA[2];
  #pragma unroll
  for (int j = 0; j < 2; j++) {
    int idx = tid + j * 256;
    int row = idx >> 2;
    int gc = (idx & 3) ^ ((row >> 1) & 3);
    int tok = gather ? perm[rowBase + row] : (rowBase + row);
    srcA[j] = (const char*)xbf + (size_t)tok * H * 2 + gc * 16;
  }
  int rowB = tid >> 2;
  int gcB = (tid & 3) ^ ((rowB >> 1) & 3);
  const char* srcBg = (const char*)Bg + (size_t)rowB * H * 2 + gcB * 16;
  const char* srcBu = (const char*)Bu + (size_t)rowB * H * 2 + gcB * 16;

  // fragment read byte-offsets within a buffer (swizzled to match)
  int offA[4], offB[2];
  #pragma unroll
  for (int m = 0; m < 4; m++) {
    int arow = wr * 64 + m * 16 + la;
    offA[m] = (arow * 4 + (ks ^ ((arow >> 1) & 3))) * 16;
  }
  #pragma unroll
  for (int n = 0; n < 2; n++) {
    int brow = wc * 32 + n * 16 + la;
    offB[n] = (brow * 4 + (ks ^ ((brow >> 1) & 3))) * 16;
  }

  f32x4 zero4 = {0.f, 0.f, 0.f, 0.f};
  f32x4 gacc[4][2], uacc[4][2];
  #pragma unroll
  for (int m = 0; m < 4; m++)
    #pragma unroll
    for (int n = 0; n < 2; n++) { gacc[m][n] = zero4; uacc[m][n] = zero4; }

  auto STAGE = [&](int p, int k0) {
    char* b = lds[p];
    gload16(srcA[0] + k0, b + wave * 1024);
    gload16(srcA[1] + k0, b + 4096 + wave * 1024);
    gload16(srcBg + k0, b + 8192 + wave * 1024);
    gload16(srcBu + k0, b + 12288 + wave * 1024);
  };

  const int NT = H / 32;  // 64
  STAGE(0, 0);
  STAGE(1, 64);
  STAGE(2, 128);
  asm volatile("s_waitcnt vmcnt(8)" ::: "memory");  // STAGE(0) done
  __builtin_amdgcn_sched_barrier(0);
  __builtin_amdgcn_s_barrier();

  for (int t = 0; t < NT; ++t) {
    const char* bufp = lds[t & 3];
    s16x8 a[4], gf[2], uf[2];
    #pragma unroll
    for (int m = 0; m < 4; m++) a[m] = *(const s16x8*)(bufp + offA[m]);
    #pragma unroll
    for (int n = 0; n < 2; n++) {
      gf[n] = *(const s16x8*)(bufp + 8192 + offB[n]);
      uf[n] = *(const s16x8*)(bufp + 12288 + offB[n]);
    }
    if (t + 3 < NT) STAGE((t + 3) & 3, (t + 3) * 64);
    asm volatile("s_waitcnt lgkmcnt(0)" ::: "memory");
    __builtin_amdgcn_sched_barrier(0);
    __builtin_amdgcn_s_setprio(1);
    #pragma unroll
    for (int m = 0; m < 4; m++) {
      #pragma unroll
      for (int n = 0; n < 2; n++) {
        gacc[m][n] = mfma16(a[m], gf[n], gacc[m][n]);
        uacc[m][n] = mfma16(a[m], uf[n], uacc[m][n]);
      }
    }
    __builtin_amdgcn_s_setprio(0);
    // ensure tile t+1 landed (all waves), then publish via barrier
    if (t + 3 < NT) { asm volatile("s_waitcnt vmcnt(8)" ::: "memory"); }
    else            { asm volatile("s_waitcnt vmcnt(0)" ::: "memory"); }
    __builtin_amdgcn_sched_barrier(0);
    __builtin_amdgcn_s_barrier();
  }

  #pragma unroll
  for (int m = 0; m < 4; m++) {
    #pragma unroll
    for (int n = 0; n < 2; n++) {
      #pragma unroll
      for (int r = 0; r < 4; r++) {
        int lr = wr * 64 + m * 16 + ks * 4 + r;
        int col = by * 64 + wc * 32 + n * 16 + la;
        float gg = gacc[m][n][r], uu = uacc[m][n][r];
        float a = gg / (1.0f + __expf(-gg)) * uu;
        if (gather && (bx * 128 + lr) >= cnt) a = 0.0f;
        act[(size_t)(rowBase + lr) * Nout + col] = f2bf(a);
      }
    }
  }
}

// ---------------- merged down GEMM, 4-buffer ring, BK=32, atomic-free ----------------
// C tile 128 rows x 64 cols. Groups: g<32 shared (by=g); else routed e,by.
// LDS buffer 12KB (A 8K @0, B 4K @8K), ring of 4 = 48KB -> 3 blocks/CU.
__global__ __launch_bounds__(256, 3) void k_down2(
    const u16* __restrict__ act_s, const u16* __restrict__ act_r,
    const u16* __restrict__ sWdT, const u16* __restrict__ WdT,
    float* __restrict__ y, u16* __restrict__ rdown,
    const float* __restrict__ wgt,
    const int* __restrict__ counts, const int* __restrict__ offs) {
  int lin = blockIdx.x;
  int xcd = lin & 7, jj = lin >> 3;
  int g = xcd + 8 * (jj % 36);   // 288 groups
  int bx = jj / 36;              // 16 row tiles
  const u16 *A, *B;
  int KD, NT, cnt, rowBase, by;
  bool routed;
  if (g < 32) {
    routed = false; by = g;
    KD = MS; NT = MS / 32;
    cnt = NTOK; rowBase = bx * 128;
    A = act_s + (size_t)rowBase * MS;
    B = sWdT + (size_t)by * 64 * MS;
  } else {
    routed = true;
    int e = (g - 32) >> 5; by = (g - 32) & 31;
    KD = MDIM; NT = MDIM / 32;
    cnt = counts[e];
    if (bx * 128 >= cnt) return;
    rowBase = offs[e] + bx * 128;
    A = act_r + (size_t)rowBase * MDIM;
    B = WdT + ((size_t)e * H + (size_t)by * 64) * MDIM;
  }

  __shared__ char lds[4][12288];

  int tid = threadIdx.x;
  int wave = tid >> 6, lane = tid & 63;
  int wr = wave >> 1, wc = wave & 1;
  int la = lane & 15, ks = lane >> 4;

  const char* srcA[2];
  #pragma unroll
  for (int j = 0; j < 2; j++) {
    int idx = tid + j * 256;
    int row = idx >> 2;
    int gc = (idx & 3) ^ ((row >> 1) & 3);
    srcA[j] = (const char*)A + (size_t)row * KD * 2 + gc * 16;
  }
  int rowB = tid >> 2;
  int gcB = (tid & 3) ^ ((rowB >> 1) & 3);
  const char* srcB = (const char*)B + (size_t)rowB * KD * 2 + gcB * 16;

  int offA[4], offB[2];
  #pragma unroll
  for (int m = 0; m < 4; m++) {
    int arow = wr * 64 + m * 16 + la;
    offA[m] = (arow * 4 + (ks ^ ((arow >> 1) & 3))) * 16;
  }
  #pragma unroll
  for (int n = 0; n < 2; n++) {
    int brow = wc * 32 + n * 16 + la;
    offB[n] = (brow * 4 + (ks ^ ((brow >> 1) & 3))) * 16;
  }

  f32x4 zero4 = {0.f, 0.f, 0.f, 0.f};
  f32x4 acc[4][2];
  #pragma unroll
  for (int m = 0; m < 4; m++)
    #pragma unroll
    for (int n = 0; n < 2; n++) acc[m][n] = zero4;

  auto STAGE = [&](int p, int k0) {
    char* b = lds[p];
    gload16(srcA[0] + k0, b + wave * 1024);
    gload16(srcA[1] + k0, b + 4096 + wave * 1024);
    gload16(srcB + k0, b + 8192 + wave * 1024);
  };

  STAGE(0, 0);
  STAGE(1, 64);
  STAGE(2, 128);
  asm volatile("s_waitcnt vmcnt(6)" ::: "memory");  // STAGE(0) done
  __builtin_amdgcn_sched_barrier(0);
  __builtin_amdgcn_s_barrier();

  for (int t = 0; t < NT; ++t) {
    const char* bufp = lds[t & 3];
    s16x8 a[4], bf[2];
    #pragma unroll
    for (int m = 0; m < 4; m++) a[m] = *(const s16x8*)(bufp + offA[m]);
    #pragma unroll
    for (int n = 0; n < 2; n++) bf[n] = *(const s16x8*)(bufp + 8192 + offB[n]);
    if (t + 3 < NT) STAGE((t + 3) & 3, (t + 3) * 64);
    asm volatile("s_waitcnt lgkmcnt(0)" ::: "memory");
    __builtin_amdgcn_sched_barrier(0);
    __builtin_amdgcn_s_setprio(1);
    #pragma unroll
    for (int m = 0; m < 4; m++)
      #pragma unroll
      for (int n = 0; n < 2; n++) acc[m][n] = mfma16(a[m], bf[n], acc[m][n]);
    __builtin_amdgcn_s_setprio(0);
    if (t + 3 < NT) { asm volatile("s_waitcnt vmcnt(6)" ::: "memory"); }
    else            { asm volatile("s_waitcnt vmcnt(0)" ::: "memory"); }
    __builtin_amdgcn_sched_barrier(0);
    __builtin_amdgcn_s_barrier();
  }

  #pragma unroll
  for (int m = 0; m < 4; m++) {
    #pragma unroll
    for (int n = 0; n < 2; n++) {
      #pragma unroll
      for (int r = 0; r < 4; r++) {
        int lr = wr * 64 + m * 16 + ks * 4 + r;
        int col = by * 64 + wc * 32 + n * 16 + la;
        float v = acc[m][n][r];
        if (routed) {
          if (bx * 128 + lr < cnt) {
            int si = rowBase + lr;
            rdown[(size_t)si * H + col] = f2bf(wgt[si] * v);
          }
        } else {
          y[(size_t)(rowBase + lr) * H + col] = v;
        }
      }
    }
  }
}

// ---------------- combine: y[tok] += rdown[slot0] + rdown[slot1] ----------------
__global__ __launch_bounds__(256) void k_combine(float* __restrict__ y,
                                                 const u16* __restrict__ rdown,
                                                 const int* __restrict__ slotmap) {
  int n = blockIdx.x;
  int s0 = slotmap[n * 2], s1 = slotmap[n * 2 + 1];
  const s16x8* r0 = (const s16x8*)(rdown + (size_t)s0 * H);
  const s16x8* r1 = (const s16x8*)(rdown + (size_t)s1 * H);
  f32x4* yp = (f32x4*)(y + (size_t)n * H);
  int t = threadIdx.x;
  s16x8 a = r0[t], b = r1[t];
  f32x4 y0 = yp[2 * t], y1 = yp[2 * t + 1];
  #pragma unroll
  for (int j = 0; j < 4; j++) {
    y0[j] += bf2f((u16)a[j]) + bf2f((u16)b[j]);
    y1[j] += bf2f((u16)a[4 + j]) + bf2f((u16)b[4 + j]);
  }
  yp[2 * t] = y0;
  yp[2 * t + 1] = y1;
}

// ---------------- host launch ----------------

extern "C" void kernel_launch(void* const* d_in, const int* in_sizes, int n_in,
                              void* d_out, int out_size, void* d_ws, size_t ws_size,
                              hipStream_t stream) {
  const float* x   = (const float*)d_in[0];
  const float* gw  = (const float*)d_in[1];
  const float* Wg  = (const float*)d_in[2];
  const float* Wu  = (const float*)d_in[3];
  const float* Wd  = (const float*)d_in[4];
  const float* sWg = (const float*)d_in[5];
  const float* sWu = (const float*)d_in[6];
  const float* sWd = (const float*)d_in[7];
  float* y = (float*)d_out;

  char* w = (char*)d_ws;
  auto alloc = [&](size_t bytes) {
    char* p = w;
    w += (bytes + 255) & ~(size_t)255;
    return p;
  };
  u16* xbf   = (u16*)alloc((size_t)NTOK * H * 2);
  u16* WgT   = (u16*)alloc((size_t)NE * MDIM * H * 2);
  u16* WuT   = (u16*)alloc((size_t)NE * MDIM * H * 2);
  u16* WdT   = (u16*)alloc((size_t)NE * H * MDIM * 2);
  u16* sWgT  = (u16*)alloc((size_t)MS * H * 2);
  u16* sWuT  = (u16*)alloc((size_t)MS * H * 2);
  u16* sWdT  = (u16*)alloc((size_t)H * MS * 2);
  u16* act_s = (u16*)alloc((size_t)NTOK * MS * 2);
  u16* act_r = (u16*)alloc((size_t)ACT_R_ROWS * MDIM * 2);
  u16* rdown = (u16*)alloc((size_t)ACT_R_ROWS * H * 2);
  int*   te      = (int*)alloc((size_t)NTOK * 2 * 4);
  float* tw      = (float*)alloc((size_t)NTOK * 2 * 4);
  int*   counts  = (int*)alloc(64);
  int*   offs    = (int*)alloc(64);
  int*   perm    = (int*)alloc((size_t)ACT_R_ROWS * 4);
  float* wgt     = (float*)alloc((size_t)ACT_R_ROWS * 4);
  int*   slotmap = (int*)alloc((size_t)NTOK * 2 * 4);

  // merged front: xlog (512 blocks) + all weight transposes (7680 blocks)
  k_front<<<NTOK / 4 + 7680, 256, 0, stream>>>(
      x, gw, xbf, te, tw, Wg, Wu, Wd, sWg, sWu, sWd,
      WgT, WuT, WdT, sWgT, sWuT, sWdT);

  // deterministic dispatch build
  k_build<<<1, 256, 0, stream>>>(te, tw, counts, offs, perm, wgt, slotmap);

  // merged shared + routed gate/up, fused SwiGLU, 4-ring BK=32 pipeline
  k_gu<<<80 * 16, 256, 0, stream>>>(
      xbf, WgT, WuT, sWgT, sWuT, act_s, act_r, perm, counts, offs);

  // merged down: shared -> dense y stores; routed -> weighted bf16 rdown stores
  k_down2<<<288 * 16, 256, 0, stream>>>(
      act_s, act_r, sWdT, WdT, y, rdown, wgt, counts, offs);

  // per-token combine of the two routed contributions
  k_combine<<<NTOK, 256, 0, stream>>>(y, rdown, slotmap);
}

// Round 11
// 154.051 us; speedup vs baseline: 1.0326x; 1.0326x over previous
//
#include <hip/hip_runtime.h>

#define H 2048
#define MDIM 512
#define NE 8
#define MS 1024
#define NTOK 2048
#define ACT_R_ROWS 5120

typedef unsigned short u16;
typedef __attribute__((ext_vector_type(4))) short s16x4;
typedef __attribute__((ext_vector_type(8))) short s16x8;
typedef __attribute__((ext_vector_type(4))) float f32x4;

__device__ inline u16 f2bf(float f) {
  unsigned u = __builtin_bit_cast(unsigned, f);
  u = (u + 0x7fffu + ((u >> 16) & 1u)) >> 16;
  return (u16)u;
}
__device__ inline float bf2f(u16 v) {
  return __builtin_bit_cast(float, (unsigned)v << 16);
}

__device__ inline f32x4 mfma16(s16x8 a, s16x8 b, f32x4 c) {
  return __builtin_amdgcn_mfma_f32_16x16x32_bf16(a, b, c, 0, 0, 0);
}

// async global->LDS, 16B per lane. LDS dest wave-uniform base (+lane*16).
__device__ inline void gload16(const void* g, void* l) {
  __builtin_amdgcn_global_load_lds(
      (const __attribute__((address_space(1))) unsigned int*)g,
      (__attribute__((address_space(3))) unsigned int*)l, 16, 0, 0);
}

// ---------------- merged front: x-convert+router logits (blocks 0..511)
// ---------------- + all 6 weight transposes (blocks 512..8191) ----------------

__device__ inline void tile_t64(const float* __restrict__ src, u16* __restrict__ dst,
                                int R, int C, int bx, int by, u16 (*tt)[66]) {
  int c0 = bx * 64, r0 = by * 64;
  int t = threadIdx.x;
  int cq = (t & 15) * 4, rr = t >> 4;
  #pragma unroll
  for (int i = 0; i < 4; i++) {
    int row = rr + i * 16;
    f32x4 v = *(const f32x4*)&src[(long)(r0 + row) * C + c0 + cq];
    tt[cq + 0][row] = f2bf(v[0]);
    tt[cq + 1][row] = f2bf(v[1]);
    tt[cq + 2][row] = f2bf(v[2]);
    tt[cq + 3][row] = f2bf(v[3]);
  }
  __syncthreads();
  int c = t >> 2, ch = t & 3;
  #pragma unroll
  for (int h = 0; h < 2; h++) {
    int chunk = ch + h * 4;
    const u16* p = &tt[c][chunk * 8];
    s16x8 o;
    #pragma unroll
    for (int w0 = 0; w0 < 8; w0++) o[w0] = (short)p[w0];
    *(s16x8*)&dst[(long)(c0 + c) * R + r0 + chunk * 8] = o;
  }
}

__global__ __launch_bounds__(256) void k_front(
    const float* __restrict__ x, const float* __restrict__ gw,
    u16* __restrict__ xbf, int* __restrict__ te, float* __restrict__ tw,
    const float* __restrict__ Wg, const float* __restrict__ Wu,
    const float* __restrict__ Wd, const float* __restrict__ sWg,
    const float* __restrict__ sWu, const float* __restrict__ sWd,
    u16* __restrict__ WgT, u16* __restrict__ WuT, u16* __restrict__ WdT,
    u16* __restrict__ sWgT, u16* __restrict__ sWuT, u16* __restrict__ sWdT) {
  __shared__ u16 tt[64][66];
  int blk = blockIdx.x;
  if (blk < NTOK / 4) {
    // ---- xlog: fused x->bf16 convert + fp64 router logits + top-2 ----
    int n = blk * 4 + (threadIdx.x >> 6);
    int lane = threadIdx.x & 63;
    double acc[NE];
    #pragma unroll
    for (int e = 0; e < NE; e++) acc[e] = 0.0;
    const f32x4* xr = (const f32x4*)(x + (size_t)n * H);
    s16x4* xo = (s16x4*)(xbf + (size_t)n * H);
    #pragma unroll
    for (int it = 0; it < H / 256; it++) {
      int j4 = it * 64 + lane;
      f32x4 v = xr[j4];
      s16x4 o;
      o[0] = (short)f2bf(v[0]); o[1] = (short)f2bf(v[1]);
      o[2] = (short)f2bf(v[2]); o[3] = (short)f2bf(v[3]);
      xo[j4] = o;
      #pragma unroll
      for (int e = 0; e < NE; e++) {
        f32x4 g = *(const f32x4*)&gw[e * H + j4 * 4];
        acc[e] += (double)v[0] * g[0] + (double)v[1] * g[1] +
                  (double)v[2] * g[2] + (double)v[3] * g[3];
      }
    }
    #pragma unroll
    for (int off = 32; off; off >>= 1) {
      #pragma unroll
      for (int e = 0; e < NE; e++) acc[e] += __shfl_xor(acc[e], off);
    }
    if (lane == 0) {
      int b0 = 0; double v0 = acc[0];
      #pragma unroll
      for (int e = 1; e < NE; e++) { if (acc[e] > v0) { v0 = acc[e]; b0 = e; } }
      int b1 = -1; double v1 = -1e300;
      #pragma unroll
      for (int e = 0; e < NE; e++) { if (e != b0 && acc[e] > v1) { v1 = acc[e]; b1 = e; } }
      double ex = exp(v1 - v0);
      te[n * 2] = b0; te[n * 2 + 1] = b1;
      tw[n * 2] = (float)(1.0 / (1.0 + ex));
      tw[n * 2 + 1] = (float)(ex / (1.0 + ex));
    }
    return;
  }
  // ---- weight transpose+convert ----
  int b = blk - NTOK / 4;
  const float* src; u16* dst; int R, C, lb;
  if (b < 2048) {
    lb = b; R = H; C = MDIM;
    int z = lb >> 8; lb &= 255;
    src = Wg + (size_t)z * H * MDIM; dst = WgT + (size_t)z * MDIM * H;
  } else if (b < 4096) {
    lb = b - 2048; R = H; C = MDIM;
    int z = lb >> 8; lb &= 255;
    src = Wu + (size_t)z * H * MDIM; dst = WuT + (size_t)z * MDIM * H;
  } else if (b < 6144) {
    lb = b - 4096; R = MDIM; C = H;
    int z = lb >> 8; lb &= 255;
    src = Wd + (size_t)z * MDIM * H; dst = WdT + (size_t)z * H * MDIM;
  } else if (b < 6656) {
    lb = b - 6144; R = H; C = MS; src = sWg; dst = sWgT;
  } else if (b < 7168) {
    lb = b - 6656; R = H; C = MS; src = sWu; dst = sWuT;
  } else {
    lb = b - 7168; R = MS; C = H; src = sWd; dst = sWdT;
  }
  int nbx = C >> 6;
  tile_t64(src, dst, R, C, lb % nbx, lb / nbx, tt);
}

// single-block deterministic dispatch build (no atomics)
__global__ __launch_bounds__(256) void k_build(
    const int* __restrict__ te, const float* __restrict__ tw,
    int* __restrict__ counts, int* __restrict__ offs,
    int* __restrict__ perm, float* __restrict__ wgt, int* __restrict__ slotmap) {
  __shared__ int cnt[256][NE];
  __shared__ int pb[NE];
  int t = threadIdx.x;
  int ebuf[16];
  int lc[NE];
  #pragma unroll
  for (int e = 0; e < NE; e++) lc[e] = 0;
  #pragma unroll
  for (int i = 0; i < 16; i++) {
    int ei = te[t * 16 + i];
    ebuf[i] = ei;
    #pragma unroll
    for (int e = 0; e < NE; e++) lc[e] += (ei == e) ? 1 : 0;
  }
  #pragma unroll
  for (int e = 0; e < NE; e++) cnt[t][e] = lc[e];
  __syncthreads();
  if (t < NE) {
    int run = 0;
    for (int i = 0; i < 256; i++) { int v = cnt[i][t]; cnt[i][t] = run; run += v; }
    counts[t] = run;
  }
  __syncthreads();
  if (t == 0) {
    int off = 0;
    #pragma unroll
    for (int e = 0; e < NE; e++) {
      pb[e] = off; offs[e] = off;
      off += ((counts[e] + 127) >> 7) << 7;
    }
    offs[NE] = off;
  }
  for (int i = t; i < ACT_R_ROWS; i += 256) { perm[i] = 0; wgt[i] = 0.f; }
  __syncthreads();
  int run2[NE];
  #pragma unroll
  for (int e = 0; e < NE; e++) run2[e] = cnt[t][e];
  #pragma unroll
  for (int i = 0; i < 16; i++) {
    int ei = ebuf[i];
    int idx = 0;
    #pragma unroll
    for (int e = 0; e < NE; e++) {
      if (ei == e) idx = pb[e] + run2[e];
      run2[e] += (ei == e) ? 1 : 0;
    }
    perm[idx] = (t * 16 + i) >> 1;
    wgt[idx] = tw[t * 16 + i];
    slotmap[t * 16 + i] = idx;
  }
}

// ---------------- fused gate+up+SwiGLU GEMM, counted-vmcnt depth-2 + stagger --------
// C tile 128 rows x 64 cols. Groups: g<16 shared; else routed e=(g-16)>>3.
// Grid 1-D 1280 = 80 groups x 16 bx, XCD-grouped. Co-resident blocks (adjacent jj)
// start the K-ring half-way apart (phase stagger) to desync barrier cadence.
__global__ __launch_bounds__(256, 2) void k_gu(
    const u16* __restrict__ xbf, const u16* __restrict__ WgT, const u16* __restrict__ WuT,
    const u16* __restrict__ sWgT, const u16* __restrict__ sWuT,
    u16* __restrict__ act_s, u16* __restrict__ act_r,
    const int* __restrict__ perm, const int* __restrict__ counts,
    const int* __restrict__ offs) {
  int lin = blockIdx.x;
  int xcd = lin & 7, jj = lin >> 3;
  int g = xcd + 8 * (jj % 10);   // 80 groups
  int bx = jj / 10;              // 16 row tiles
  const u16 *Bg, *Bu;
  u16* act;
  int Nout, cnt, rowBase, by;
  bool gather;
  if (g < 16) {
    gather = false; by = g;
    cnt = NTOK; rowBase = bx * 128;
    Bg = sWgT + (size_t)by * 64 * H;
    Bu = sWuT + (size_t)by * 64 * H;
    act = act_s; Nout = MS;
  } else {
    gather = true;
    int e = (g - 16) >> 3; by = (g - 16) & 7;
    cnt = counts[e];
    if (bx * 128 >= cnt) return;
    rowBase = offs[e] + bx * 128;
    Bg = WgT + ((size_t)e * MDIM + (size_t)by * 64) * H;
    Bu = WuT + ((size_t)e * MDIM + (size_t)by * 64) * H;
    act = act_r; Nout = MDIM;
  }

  __shared__ char lds[2][32768];  // A:0..16K, Bg:16K..24K, Bu:24K..32K

  int tid = threadIdx.x;
  int wave = tid >> 6, lane = tid & 63;
  int wr = wave >> 1, wc = wave & 1;
  int la = lane & 15, ks = lane >> 4;

  int rIn = tid >> 3;
  int csrc = ((tid & 7) << 4) ^ ((rIn & 7) << 4);
  const char* srcA[4];
  const char* srcBg[2];
  const char* srcBu[2];
  #pragma unroll
  for (int j = 0; j < 4; j++) {
    int row = j * 32 + rIn;
    int tok = gather ? perm[rowBase + row] : (rowBase + row);
    srcA[j] = (const char*)xbf + (size_t)tok * H * 2 + csrc;
  }
  #pragma unroll
  for (int j = 0; j < 2; j++) {
    int row = j * 32 + rIn;
    srcBg[j] = (const char*)Bg + (size_t)row * H * 2 + csrc;
    srcBu[j] = (const char*)Bu + (size_t)row * H * 2 + csrc;
  }

  int offA[4][2], offB[2][2];
  #pragma unroll
  for (int m = 0; m < 4; m++) {
    int arow = wr * 64 + m * 16 + la;
    #pragma unroll
    for (int kk = 0; kk < 2; kk++) {
      int c = kk * 64 + ks * 16;
      offA[m][kk] = arow * 128 + (c ^ ((arow & 7) << 4));
    }
  }
  #pragma unroll
  for (int n = 0; n < 2; n++) {
    int brow = wc * 32 + n * 16 + la;
    #pragma unroll
    for (int kk = 0; kk < 2; kk++) {
      int c = kk * 64 + ks * 16;
      offB[n][kk] = brow * 128 + (c ^ ((brow & 7) << 4));
    }
  }

  f32x4 zero4 = {0.f, 0.f, 0.f, 0.f};
  f32x4 gacc[4][2], uacc[4][2];
  #pragma unroll
  for (int m = 0; m < 4; m++)
    #pragma unroll
    for (int n = 0; n < 2; n++) { gacc[m][n] = zero4; uacc[m][n] = zero4; }

  auto STAGE = [&](int p, int k0) {
    char* b = lds[p];
    #pragma unroll
    for (int j = 0; j < 4; j++)
      gload16(srcA[j] + k0, b + j * 4096 + wave * 1024);
    #pragma unroll
    for (int j = 0; j < 2; j++) {
      gload16(srcBg[j] + k0, b + 16384 + j * 4096 + wave * 1024);
      gload16(srcBu[j] + k0, b + 24576 + j * 4096 + wave * 1024);
    }
  };

  const int NT = H / 64;  // 32
  int phase = ((lin >> 3) & 1) * (NT / 2);  // adjacent jj -> opposite K-ring halves
  auto KOF = [&](int s) { int v = s + phase; if (v >= NT) v -= NT; return v * 128; };

  STAGE(0, KOF(0));
  STAGE(1, KOF(1));
  asm volatile("s_waitcnt vmcnt(8)" ::: "memory");
  __builtin_amdgcn_sched_barrier(0);
  __builtin_amdgcn_s_barrier();

  for (int t = 0; t < NT; ++t) {
    int p = t & 1;
    const char* A = lds[p];
    const char* G = lds[p] + 16384;
    const char* U = lds[p] + 24576;
    s16x8 af[2][4], gf[2][2], uf[2][2];
    // kk0 frag reads first (order pinned), then kk1
    #pragma unroll
    for (int m = 0; m < 4; m++) af[0][m] = *(const s16x8*)(A + offA[m][0]);
    #pragma unroll
    for (int n = 0; n < 2; n++) {
      gf[0][n] = *(const s16x8*)(G + offB[n][0]);
      uf[0][n] = *(const s16x8*)(U + offB[n][0]);
    }
    __builtin_amdgcn_sched_barrier(0);
    #pragma unroll
    for (int m = 0; m < 4; m++) af[1][m] = *(const s16x8*)(A + offA[m][1]);
    #pragma unroll
    for (int n = 0; n < 2; n++) {
      gf[1][n] = *(const s16x8*)(G + offB[n][1]);
      uf[1][n] = *(const s16x8*)(U + offB[n][1]);
    }
    asm volatile("s_waitcnt lgkmcnt(8)" ::: "memory");  // kk0 frags landed
    __builtin_amdgcn_sched_barrier(0);
    __builtin_amdgcn_s_setprio(1);
    #pragma unroll
    for (int m = 0; m < 4; m++) {
      #pragma unroll
      for (int n = 0; n < 2; n++) {
        gacc[m][n] = mfma16(af[0][m], gf[0][n], gacc[m][n]);
        uacc[m][n] = mfma16(af[0][m], uf[0][n], uacc[m][n]);
      }
    }
    __builtin_amdgcn_s_setprio(0);
    asm volatile("s_waitcnt lgkmcnt(0)" ::: "memory");
    __builtin_amdgcn_sched_barrier(0);
    __builtin_amdgcn_s_barrier();             // all waves done reading buf p
    if (t + 2 < NT) STAGE(p, KOF(t + 2));     // overwrite buf p (reads retired)
    __builtin_amdgcn_sched_barrier(0);
    __builtin_amdgcn_s_setprio(1);
    #pragma unroll
    for (int m = 0; m < 4; m++) {
      #pragma unroll
      for (int n = 0; n < 2; n++) {
        gacc[m][n] = mfma16(af[1][m], gf[1][n], gacc[m][n]);
        uacc[m][n] = mfma16(af[1][m], uf[1][n], uacc[m][n]);
      }
    }
    __builtin_amdgcn_s_setprio(0);
    if (t + 2 < NT) { asm volatile("s_waitcnt vmcnt(8)" ::: "memory"); }
    else            { asm volatile("s_waitcnt vmcnt(0)" ::: "memory"); }
    __builtin_amdgcn_sched_barrier(0);
    __builtin_amdgcn_s_barrier();             // publish buf p^1 (tile t+1)
  }

  #pragma unroll
  for (int m = 0; m < 4; m++) {
    #pragma unroll
    for (int n = 0; n < 2; n++) {
      #pragma unroll
      for (int r = 0; r < 4; r++) {
        int lr = wr * 64 + m * 16 + ks * 4 + r;
        int col = by * 64 + wc * 32 + n * 16 + la;
        float gg = gacc[m][n][r], uu = uacc[m][n][r];
        float a = gg / (1.0f + __expf(-gg)) * uu;
        if (gather && (bx * 128 + lr) >= cnt) a = 0.0f;
        act[(size_t)(rowBase + lr) * Nout + col] = f2bf(a);
      }
    }
  }
}

// ---------------- merged down GEMM, counted-vmcnt depth-2 + stagger, atomic-free ----
// C tile 128 rows x 64 cols. Groups: g<32 shared (by=g); else routed e,by.
// Grid 1-D 4608 = 288 groups x 16 bx, XCD-grouped.
__global__ __launch_bounds__(256, 3) void k_down2(
    const u16* __restrict__ act_s, const u16* __restrict__ act_r,
    const u16* __restrict__ sWdT, const u16* __restrict__ WdT,
    float* __restrict__ y, u16* __restrict__ rdown,
    const float* __restrict__ wgt,
    const int* __restrict__ counts, const int* __restrict__ offs) {
  int lin = blockIdx.x;
  int xcd = lin & 7, jj = lin >> 3;
  int g = xcd + 8 * (jj % 36);   // 288 groups
  int bx = jj / 36;              // 16 row tiles
  const u16 *A, *B;
  int KD, NT, cnt, rowBase, by;
  bool routed;
  if (g < 32) {
    routed = false; by = g;
    KD = MS; NT = MS / 64;
    cnt = NTOK; rowBase = bx * 128;
    A = act_s + (size_t)rowBase * MS;
    B = sWdT + (size_t)by * 64 * MS;
  } else {
    routed = true;
    int e = (g - 32) >> 5; by = (g - 32) & 31;
    KD = MDIM; NT = MDIM / 64;
    cnt = counts[e];
    if (bx * 128 >= cnt) return;
    rowBase = offs[e] + bx * 128;
    A = act_r + (size_t)rowBase * MDIM;
    B = WdT + ((size_t)e * H + (size_t)by * 64) * MDIM;
  }

  __shared__ char lds[2][24576];  // A:0..16K, B:16K..24K

  int tid = threadIdx.x;
  int wave = tid >> 6, lane = tid & 63;
  int wr = wave >> 1, wc = wave & 1;
  int la = lane & 15, ks = lane >> 4;

  int rIn = tid >> 3;
  int csrc = ((tid & 7) << 4) ^ ((rIn & 7) << 4);
  const char* srcA[4];
  const char* srcB[2];
  #pragma unroll
  for (int j = 0; j < 4; j++) {
    int row = j * 32 + rIn;
    srcA[j] = (const char*)A + (size_t)row * KD * 2 + csrc;
  }
  #pragma unroll
  for (int j = 0; j < 2; j++) {
    int row = j * 32 + rIn;
    srcB[j] = (const char*)B + (size_t)row * KD * 2 + csrc;
  }

  int offA[4][2], offB[2][2];
  #pragma unroll
  for (int m = 0; m < 4; m++) {
    int arow = wr * 64 + m * 16 + la;
    #pragma unroll
    for (int kk = 0; kk < 2; kk++) {
      int c = kk * 64 + ks * 16;
      offA[m][kk] = arow * 128 + (c ^ ((arow & 7) << 4));
    }
  }
  #pragma unroll
  for (int n = 0; n < 2; n++) {
    int brow = wc * 32 + n * 16 + la;
    #pragma unroll
    for (int kk = 0; kk < 2; kk++) {
      int c = kk * 64 + ks * 16;
      offB[n][kk] = brow * 128 + (c ^ ((brow & 7) << 4));
    }
  }

  f32x4 zero4 = {0.f, 0.f, 0.f, 0.f};
  f32x4 acc[4][2];
  #pragma unroll
  for (int m = 0; m < 4; m++)
    #pragma unroll
    for (int n = 0; n < 2; n++) acc[m][n] = zero4;

  auto STAGE = [&](int p, int k0) {
    char* b = lds[p];
    #pragma unroll
    for (int j = 0; j < 4; j++)
      gload16(srcA[j] + k0, b + j * 4096 + wave * 1024);
    #pragma unroll
    for (int j = 0; j < 2; j++)
      gload16(srcB[j] + k0, b + 16384 + j * 4096 + wave * 1024);
  };

  int phase = ((lin >> 3) & 1) * (NT / 2);
  auto KOF = [&](int s) { int v = s + phase; if (v >= NT) v -= NT; return v * 128; };

  STAGE(0, KOF(0));
  STAGE(1, KOF(1));
  asm volatile("s_waitcnt vmcnt(6)" ::: "memory");
  __builtin_amdgcn_sched_barrier(0);
  __builtin_amdgcn_s_barrier();

  for (int t = 0; t < NT; ++t) {
    int p = t & 1;
    const char* Ab = lds[p];
    const char* Bb = lds[p] + 16384;
    s16x8 af[2][4], bf[2][2];
    #pragma unroll
    for (int m = 0; m < 4; m++) af[0][m] = *(const s16x8*)(Ab + offA[m][0]);
    #pragma unroll
    for (int n = 0; n < 2; n++) bf[0][n] = *(const s16x8*)(Bb + offB[n][0]);
    __builtin_amdgcn_sched_barrier(0);
    #pragma unroll
    for (int m = 0; m < 4; m++) af[1][m] = *(const s16x8*)(Ab + offA[m][1]);
    #pragma unroll
    for (int n = 0; n < 2; n++) bf[1][n] = *(const s16x8*)(Bb + offB[n][1]);
    asm volatile("s_waitcnt lgkmcnt(6)" ::: "memory");  // kk0 frags landed
    __builtin_amdgcn_sched_barrier(0);
    __builtin_amdgcn_s_setprio(1);
    #pragma unroll
    for (int m = 0; m < 4; m++)
      #pragma unroll
      for (int n = 0; n < 2; n++) acc[m][n] = mfma16(af[0][m], bf[0][n], acc[m][n]);
    __builtin_amdgcn_s_setprio(0);
    asm volatile("s_waitcnt lgkmcnt(0)" ::: "memory");
    __builtin_amdgcn_sched_barrier(0);
    __builtin_amdgcn_s_barrier();
    if (t + 2 < NT) STAGE(p, KOF(t + 2));
    __builtin_amdgcn_sched_barrier(0);
    __builtin_amdgcn_s_setprio(1);
    #pragma unroll
    for (int m = 0; m < 4; m++)
      #pragma unroll
      for (int n = 0; n < 2; n++) acc[m][n] = mfma16(af[1][m], bf[1][n], acc[m][n]);
    __builtin_amdgcn_s_setprio(0);
    if (t + 2 < NT) { asm volatile("s_waitcnt vmcnt(6)" ::: "memory"); }
    else            { asm volatile("s_waitcnt vmcnt(0)" ::: "memory"); }
    __builtin_amdgcn_sched_barrier(0);
    __builtin_amdgcn_s_barrier();
  }

  #pragma unroll
  for (int m = 0; m < 4; m++) {
    #pragma unroll
    for (int n = 0; n < 2; n++) {
      #pragma unroll
      for (int r = 0; r < 4; r++) {
        int lr = wr * 64 + m * 16 + ks * 4 + r;
        int col = by * 64 + wc * 32 + n * 16 + la;
        float v = acc[m][n][r];
        if (routed) {
          if (bx * 128 + lr < cnt) {
            int si = rowBase + lr;
            rdown[(size_t)si * H + col] = f2bf(wgt[si] * v);
          }
        } else {
          y[(size_t)(rowBase + lr) * H + col] = v;
        }
      }
    }
  }
}

// ---------------- combine: y[tok] += rdown[slot0] + rdown[slot1] ----------------
__global__ __launch_bounds__(256) void k_combine(float* __restrict__ y,
                                                 const u16* __restrict__ rdown,
                                                 const int* __restrict__ slotmap) {
  int n = blockIdx.x;
  int s0 = slotmap[n * 2], s1 = slotmap[n * 2 + 1];
  const s16x8* r0 = (const s16x8*)(rdown + (size_t)s0 * H);
  const s16x8* r1 = (const s16x8*)(rdown + (size_t)s1 * H);
  f32x4* yp = (f32x4*)(y + (size_t)n * H);
  int t = threadIdx.x;
  s16x8 a = r0[t], b = r1[t];
  f32x4 y0 = yp[2 * t], y1 = yp[2 * t + 1];
  #pragma unroll
  for (int j = 0; j < 4; j++) {
    y0[j] += bf2f((u16)a[j]) + bf2f((u16)b[j]);
    y1[j] += bf2f((u16)a[4 + j]) + bf2f((u16)b[4 + j]);
  }
  yp[2 * t] = y0;
  yp[2 * t + 1] = y1;
}

// ---------------- host launch ----------------

extern "C" void kernel_launch(void* const* d_in, const int* in_sizes, int n_in,
                              void* d_out, int out_size, void* d_ws, size_t ws_size,
                              hipStream_t stream) {
  const float* x   = (const float*)d_in[0];
  const float* gw  = (const float*)d_in[1];
  const float* Wg  = (const float*)d_in[2];
  const float* Wu  = (const float*)d_in[3];
  const float* Wd  = (const float*)d_in[4];
  const float* sWg = (const float*)d_in[5];
  const float* sWu = (const float*)d_in[6];
  const float* sWd = (const float*)d_in[7];
  float* y = (float*)d_out;

  char* w = (char*)d_ws;
  auto alloc = [&](size_t bytes) {
    char* p = w;
    w += (bytes + 255) & ~(size_t)255;
    return p;
  };
  u16* xbf   = (u16*)alloc((size_t)NTOK * H * 2);
  u16* WgT   = (u16*)alloc((size_t)NE * MDIM * H * 2);
  u16* WuT   = (u16*)alloc((size_t)NE * MDIM * H * 2);
  u16* WdT   = (u16*)alloc((size_t)NE * H * MDIM * 2);
  u16* sWgT  = (u16*)alloc((size_t)MS * H * 2);
  u16* sWuT  = (u16*)alloc((size_t)MS * H * 2);
  u16* sWdT  = (u16*)alloc((size_t)H * MS * 2);
  u16* act_s = (u16*)alloc((size_t)NTOK * MS * 2);
  u16* act_r = (u16*)alloc((size_t)ACT_R_ROWS * MDIM * 2);
  u16* rdown = (u16*)alloc((size_t)ACT_R_ROWS * H * 2);
  int*   te      = (int*)alloc((size_t)NTOK * 2 * 4);
  float* tw      = (float*)alloc((size_t)NTOK * 2 * 4);
  int*   counts  = (int*)alloc(64);
  int*   offs    = (int*)alloc(64);
  int*   perm    = (int*)alloc((size_t)ACT_R_ROWS * 4);
  float* wgt     = (float*)alloc((size_t)ACT_R_ROWS * 4);
  int*   slotmap = (int*)alloc((size_t)NTOK * 2 * 4);

  // merged front: xlog (512 blocks) + all weight transposes (7680 blocks)
  k_front<<<NTOK / 4 + 7680, 256, 0, stream>>>(
      x, gw, xbf, te, tw, Wg, Wu, Wd, sWg, sWu, sWd,
      WgT, WuT, WdT, sWgT, sWuT, sWdT);

  // deterministic dispatch build
  k_build<<<1, 256, 0, stream>>>(te, tw, counts, offs, perm, wgt, slotmap);

  // merged shared + routed gate/up, fused SwiGLU, counted-vmcnt + stagger
  k_gu<<<80 * 16, 256, 0, stream>>>(
      xbf, WgT, WuT, sWgT, sWuT, act_s, act_r, perm, counts, offs);

  // merged down: shared -> dense y stores; routed -> weighted bf16 rdown stores
  k_down2<<<288 * 16, 256, 0, stream>>>(
      act_s, act_r, sWdT, WdT, y, rdown, wgt, counts, offs);

  // per-token combine of the two routed contributions
  k_combine<<<NTOK, 256, 0, stream>>>(y, rdown, slotmap);
}

// Round 12
// 144.120 us; speedup vs baseline: 1.1038x; 1.0689x over previous
//
#include <hip/hip_runtime.h>

#define H 2048
#define MDIM 512
#define NE 8
#define MS 1024
#define NTOK 2048
#define ACT_R_ROWS 5120

typedef unsigned short u16;
typedef __attribute__((ext_vector_type(4))) short s16x4;
typedef __attribute__((ext_vector_type(8))) short s16x8;
typedef __attribute__((ext_vector_type(4))) float f32x4;

__device__ inline u16 f2bf(float f) {
  unsigned u = __builtin_bit_cast(unsigned, f);
  u = (u + 0x7fffu + ((u >> 16) & 1u)) >> 16;
  return (u16)u;
}
__device__ inline float bf2f(u16 v) {
  return __builtin_bit_cast(float, (unsigned)v << 16);
}

__device__ inline f32x4 mfma16(s16x8 a, s16x8 b, f32x4 c) {
  return __builtin_amdgcn_mfma_f32_16x16x32_bf16(a, b, c, 0, 0, 0);
}

// async global->LDS, 16B per lane. LDS dest wave-uniform base (+lane*16).
__device__ inline void gload16(const void* g, void* l) {
  __builtin_amdgcn_global_load_lds(
      (const __attribute__((address_space(1))) unsigned int*)g,
      (__attribute__((address_space(3))) unsigned int*)l, 16, 0, 0);
}

// ---------------- merged front: x-convert+router logits (blocks 0..511)
// ---------------- + all 6 weight transposes (blocks 512..8191) ----------------

__device__ inline void tile_t64(const float* __restrict__ src, u16* __restrict__ dst,
                                int R, int C, int bx, int by, u16 (*tt)[66]) {
  int c0 = bx * 64, r0 = by * 64;
  int t = threadIdx.x;
  int cq = (t & 15) * 4, rr = t >> 4;
  #pragma unroll
  for (int i = 0; i < 4; i++) {
    int row = rr + i * 16;
    f32x4 v = *(const f32x4*)&src[(long)(r0 + row) * C + c0 + cq];
    tt[cq + 0][row] = f2bf(v[0]);
    tt[cq + 1][row] = f2bf(v[1]);
    tt[cq + 2][row] = f2bf(v[2]);
    tt[cq + 3][row] = f2bf(v[3]);
  }
  __syncthreads();
  int c = t >> 2, ch = t & 3;
  #pragma unroll
  for (int h = 0; h < 2; h++) {
    int chunk = ch + h * 4;
    const u16* p = &tt[c][chunk * 8];
    s16x8 o;
    #pragma unroll
    for (int w0 = 0; w0 < 8; w0++) o[w0] = (short)p[w0];
    *(s16x8*)&dst[(long)(c0 + c) * R + r0 + chunk * 8] = o;
  }
}

__global__ __launch_bounds__(256) void k_front(
    const float* __restrict__ x, const float* __restrict__ gw,
    u16* __restrict__ xbf, int* __restrict__ te, float* __restrict__ tw,
    const float* __restrict__ Wg, const float* __restrict__ Wu,
    const float* __restrict__ Wd, const float* __restrict__ sWg,
    const float* __restrict__ sWu, const float* __restrict__ sWd,
    u16* __restrict__ WgT, u16* __restrict__ WuT, u16* __restrict__ WdT,
    u16* __restrict__ sWgT, u16* __restrict__ sWuT, u16* __restrict__ sWdT) {
  __shared__ u16 tt[64][66];
  int blk = blockIdx.x;
  if (blk < NTOK / 4) {
    // ---- xlog: fused x->bf16 convert + fp64 router logits + top-2 ----
    int n = blk * 4 + (threadIdx.x >> 6);
    int lane = threadIdx.x & 63;
    double acc[NE];
    #pragma unroll
    for (int e = 0; e < NE; e++) acc[e] = 0.0;
    const f32x4* xr = (const f32x4*)(x + (size_t)n * H);
    s16x4* xo = (s16x4*)(xbf + (size_t)n * H);
    #pragma unroll
    for (int it = 0; it < H / 256; it++) {
      int j4 = it * 64 + lane;
      f32x4 v = xr[j4];
      s16x4 o;
      o[0] = (short)f2bf(v[0]); o[1] = (short)f2bf(v[1]);
      o[2] = (short)f2bf(v[2]); o[3] = (short)f2bf(v[3]);
      xo[j4] = o;
      #pragma unroll
      for (int e = 0; e < NE; e++) {
        f32x4 g = *(const f32x4*)&gw[e * H + j4 * 4];
        acc[e] += (double)v[0] * g[0] + (double)v[1] * g[1] +
                  (double)v[2] * g[2] + (double)v[3] * g[3];
      }
    }
    #pragma unroll
    for (int off = 32; off; off >>= 1) {
      #pragma unroll
      for (int e = 0; e < NE; e++) acc[e] += __shfl_xor(acc[e], off);
    }
    if (lane == 0) {
      int b0 = 0; double v0 = acc[0];
      #pragma unroll
      for (int e = 1; e < NE; e++) { if (acc[e] > v0) { v0 = acc[e]; b0 = e; } }
      int b1 = -1; double v1 = -1e300;
      #pragma unroll
      for (int e = 0; e < NE; e++) { if (e != b0 && acc[e] > v1) { v1 = acc[e]; b1 = e; } }
      double ex = exp(v1 - v0);
      te[n * 2] = b0; te[n * 2 + 1] = b1;
      tw[n * 2] = (float)(1.0 / (1.0 + ex));
      tw[n * 2 + 1] = (float)(ex / (1.0 + ex));
    }
    return;
  }
  // ---- weight transpose+convert ----
  int b = blk - NTOK / 4;
  const float* src; u16* dst; int R, C, lb;
  if (b < 2048) {
    lb = b; R = H; C = MDIM;
    int z = lb >> 8; lb &= 255;
    src = Wg + (size_t)z * H * MDIM; dst = WgT + (size_t)z * MDIM * H;
  } else if (b < 4096) {
    lb = b - 2048; R = H; C = MDIM;
    int z = lb >> 8; lb &= 255;
    src = Wu + (size_t)z * H * MDIM; dst = WuT + (size_t)z * MDIM * H;
  } else if (b < 6144) {
    lb = b - 4096; R = MDIM; C = H;
    int z = lb >> 8; lb &= 255;
    src = Wd + (size_t)z * MDIM * H; dst = WdT + (size_t)z * H * MDIM;
  } else if (b < 6656) {
    lb = b - 6144; R = H; C = MS; src = sWg; dst = sWgT;
  } else if (b < 7168) {
    lb = b - 6656; R = H; C = MS; src = sWu; dst = sWuT;
  } else {
    lb = b - 7168; R = MS; C = H; src = sWd; dst = sWdT;
  }
  int nbx = C >> 6;
  tile_t64(src, dst, R, C, lb % nbx, lb / nbx, tt);
}

// single-block deterministic dispatch build (no atomics)
__global__ __launch_bounds__(256) void k_build(
    const int* __restrict__ te, const float* __restrict__ tw,
    int* __restrict__ counts, int* __restrict__ offs,
    int* __restrict__ perm, float* __restrict__ wgt, int* __restrict__ slotmap) {
  __shared__ int cnt[256][NE];
  __shared__ int pb[NE];
  int t = threadIdx.x;
  int ebuf[16];
  int lc[NE];
  #pragma unroll
  for (int e = 0; e < NE; e++) lc[e] = 0;
  #pragma unroll
  for (int i = 0; i < 16; i++) {
    int ei = te[t * 16 + i];
    ebuf[i] = ei;
    #pragma unroll
    for (int e = 0; e < NE; e++) lc[e] += (ei == e) ? 1 : 0;
  }
  #pragma unroll
  for (int e = 0; e < NE; e++) cnt[t][e] = lc[e];
  __syncthreads();
  if (t < NE) {
    int run = 0;
    for (int i = 0; i < 256; i++) { int v = cnt[i][t]; cnt[i][t] = run; run += v; }
    counts[t] = run;
  }
  __syncthreads();
  if (t == 0) {
    int off = 0;
    #pragma unroll
    for (int e = 0; e < NE; e++) {
      pb[e] = off; offs[e] = off;
      off += ((counts[e] + 127) >> 7) << 7;
    }
    offs[NE] = off;
  }
  for (int i = t; i < ACT_R_ROWS; i += 256) { perm[i] = 0; wgt[i] = 0.f; }
  __syncthreads();
  int run2[NE];
  #pragma unroll
  for (int e = 0; e < NE; e++) run2[e] = cnt[t][e];
  #pragma unroll
  for (int i = 0; i < 16; i++) {
    int ei = ebuf[i];
    int idx = 0;
    #pragma unroll
    for (int e = 0; e < NE; e++) {
      if (ei == e) idx = pb[e] + run2[e];
      run2[e] += (ei == e) ? 1 : 0;
    }
    perm[idx] = (t * 16 + i) >> 1;
    wgt[idx] = tw[t * 16 + i];
    slotmap[t * 16 + i] = idx;
  }
}

// ---------------- fused gate+up+SwiGLU GEMM, counted-vmcnt depth-2 (round-9) --------
// C tile 128 rows x 64 cols. Groups: g<16 shared; else routed e=(g-16)>>3.
// Grid 1-D 1280 = 80 groups x 16 bx, XCD-grouped. T5 setprio around MFMA.
__global__ __launch_bounds__(256, 2) void k_gu(
    const u16* __restrict__ xbf, const u16* __restrict__ WgT, const u16* __restrict__ WuT,
    const u16* __restrict__ sWgT, const u16* __restrict__ sWuT,
    u16* __restrict__ act_s, u16* __restrict__ act_r,
    const int* __restrict__ perm, const int* __restrict__ counts,
    const int* __restrict__ offs) {
  int lin = blockIdx.x;
  int xcd = lin & 7, jj = lin >> 3;
  int g = xcd + 8 * (jj % 10);   // 80 groups
  int bx = jj / 10;              // 16 row tiles
  const u16 *Bg, *Bu;
  u16* act;
  int Nout, cnt, rowBase, by;
  bool gather;
  if (g < 16) {
    gather = false; by = g;
    cnt = NTOK; rowBase = bx * 128;
    Bg = sWgT + (size_t)by * 64 * H;
    Bu = sWuT + (size_t)by * 64 * H;
    act = act_s; Nout = MS;
  } else {
    gather = true;
    int e = (g - 16) >> 3; by = (g - 16) & 7;
    cnt = counts[e];
    if (bx * 128 >= cnt) return;
    rowBase = offs[e] + bx * 128;
    Bg = WgT + ((size_t)e * MDIM + (size_t)by * 64) * H;
    Bu = WuT + ((size_t)e * MDIM + (size_t)by * 64) * H;
    act = act_r; Nout = MDIM;
  }

  __shared__ char lds[2][32768];  // A:0..16K, Bg:16K..24K, Bu:24K..32K

  int tid = threadIdx.x;
  int wave = tid >> 6, lane = tid & 63;
  int wr = wave >> 1, wc = wave & 1;
  int la = lane & 15, ks = lane >> 4;

  int rIn = tid >> 3;
  int csrc = ((tid & 7) << 4) ^ ((rIn & 7) << 4);
  const char* srcA[4];
  const char* srcBg[2];
  const char* srcBu[2];
  #pragma unroll
  for (int j = 0; j < 4; j++) {
    int row = j * 32 + rIn;
    int tok = gather ? perm[rowBase + row] : (rowBase + row);
    srcA[j] = (const char*)xbf + (size_t)tok * H * 2 + csrc;
  }
  #pragma unroll
  for (int j = 0; j < 2; j++) {
    int row = j * 32 + rIn;
    srcBg[j] = (const char*)Bg + (size_t)row * H * 2 + csrc;
    srcBu[j] = (const char*)Bu + (size_t)row * H * 2 + csrc;
  }

  int offA[4][2], offB[2][2];
  #pragma unroll
  for (int m = 0; m < 4; m++) {
    int arow = wr * 64 + m * 16 + la;
    #pragma unroll
    for (int kk = 0; kk < 2; kk++) {
      int c = kk * 64 + ks * 16;
      offA[m][kk] = arow * 128 + (c ^ ((arow & 7) << 4));
    }
  }
  #pragma unroll
  for (int n = 0; n < 2; n++) {
    int brow = wc * 32 + n * 16 + la;
    #pragma unroll
    for (int kk = 0; kk < 2; kk++) {
      int c = kk * 64 + ks * 16;
      offB[n][kk] = brow * 128 + (c ^ ((brow & 7) << 4));
    }
  }

  f32x4 zero4 = {0.f, 0.f, 0.f, 0.f};
  f32x4 gacc[4][2], uacc[4][2];
  #pragma unroll
  for (int m = 0; m < 4; m++)
    #pragma unroll
    for (int n = 0; n < 2; n++) { gacc[m][n] = zero4; uacc[m][n] = zero4; }

  auto STAGE = [&](int p, int k0) {
    char* b = lds[p];
    #pragma unroll
    for (int j = 0; j < 4; j++)
      gload16(srcA[j] + k0, b + j * 4096 + wave * 1024);
    #pragma unroll
    for (int j = 0; j < 2; j++) {
      gload16(srcBg[j] + k0, b + 16384 + j * 4096 + wave * 1024);
      gload16(srcBu[j] + k0, b + 24576 + j * 4096 + wave * 1024);
    }
  };

  const int NT = H / 64;  // 32
  STAGE(0, 0);
  STAGE(1, 128);
  asm volatile("s_waitcnt vmcnt(8)" ::: "memory");
  __builtin_amdgcn_sched_barrier(0);
  __builtin_amdgcn_s_barrier();

  for (int t = 0; t < NT; ++t) {
    int p = t & 1;
    const char* A = lds[p];
    const char* G = lds[p] + 16384;
    const char* U = lds[p] + 24576;
    s16x8 af[2][4], gf[2][2], uf[2][2];
    #pragma unroll
    for (int kk = 0; kk < 2; kk++) {
      #pragma unroll
      for (int m = 0; m < 4; m++) af[kk][m] = *(const s16x8*)(A + offA[m][kk]);
      #pragma unroll
      for (int n = 0; n < 2; n++) {
        gf[kk][n] = *(const s16x8*)(G + offB[n][kk]);
        uf[kk][n] = *(const s16x8*)(U + offB[n][kk]);
      }
    }
    asm volatile("s_waitcnt lgkmcnt(0)" ::: "memory");
    __builtin_amdgcn_sched_barrier(0);
    __builtin_amdgcn_s_barrier();           // all waves done reading buf p
    if (t + 2 < NT) STAGE(p, (t + 2) * 128);  // overwrite buf p (reads retired)
    __builtin_amdgcn_sched_barrier(0);
    __builtin_amdgcn_s_setprio(1);
    #pragma unroll
    for (int kk = 0; kk < 2; kk++) {
      #pragma unroll
      for (int m = 0; m < 4; m++) {
        #pragma unroll
        for (int n = 0; n < 2; n++) {
          gacc[m][n] = mfma16(af[kk][m], gf[kk][n], gacc[m][n]);
          uacc[m][n] = mfma16(af[kk][m], uf[kk][n], uacc[m][n]);
        }
      }
    }
    __builtin_amdgcn_s_setprio(0);
    if (t + 2 < NT) { asm volatile("s_waitcnt vmcnt(8)" ::: "memory"); }
    else            { asm volatile("s_waitcnt vmcnt(0)" ::: "memory"); }
    __builtin_amdgcn_sched_barrier(0);
    __builtin_amdgcn_s_barrier();           // publish buf p^1 (tile t+1)
  }

  #pragma unroll
  for (int m = 0; m < 4; m++) {
    #pragma unroll
    for (int n = 0; n < 2; n++) {
      #pragma unroll
      for (int r = 0; r < 4; r++) {
        int lr = wr * 64 + m * 16 + ks * 4 + r;
        int col = by * 64 + wc * 32 + n * 16 + la;
        float gg = gacc[m][n][r], uu = uacc[m][n][r];
        float a = gg / (1.0f + __expf(-gg)) * uu;
        if (gather && (bx * 128 + lr) >= cnt) a = 0.0f;
        act[(size_t)(rowBase + lr) * Nout + col] = f2bf(a);
      }
    }
  }
}

// ---------------- merged down GEMM: 128x128 block, wave 64x64, atomic-free ----------
// 144 groups (16 shared-by + 8e x 16by routed) x 16 bx = 2304 blocks, XCD-grouped.
// LDS 2 x (A 16K + B 16K) = 64 KB (2 blocks/CU). Counted vmcnt(8), split lgkm.
__global__ __launch_bounds__(256, 2) void k_down2(
    const u16* __restrict__ act_s, const u16* __restrict__ act_r,
    const u16* __restrict__ sWdT, const u16* __restrict__ WdT,
    float* __restrict__ y, u16* __restrict__ rdown,
    const float* __restrict__ wgt,
    const int* __restrict__ counts, const int* __restrict__ offs) {
  int lin = blockIdx.x;
  int xcd = lin & 7, jj = lin >> 3;
  int g = xcd + 8 * (jj % 18);   // 144 groups
  int bx = jj / 18;              // 16 row tiles
  const u16 *A, *B;
  int KD, NT, cnt, rowBase, by;
  bool routed;
  if (g < 16) {
    routed = false; by = g;
    KD = MS; NT = MS / 64;
    cnt = NTOK; rowBase = bx * 128;
    A = act_s + (size_t)rowBase * MS;
    B = sWdT + (size_t)by * 128 * MS;
  } else {
    routed = true;
    int e = (g - 16) >> 4; by = (g - 16) & 15;
    KD = MDIM; NT = MDIM / 64;
    cnt = counts[e];
    if (bx * 128 >= cnt) return;
    rowBase = offs[e] + bx * 128;
    A = act_r + (size_t)rowBase * MDIM;
    B = WdT + ((size_t)e * H + (size_t)by * 128) * MDIM;
  }

  __shared__ char lds[2][32768];  // A:0..16K, B:16K..32K

  int tid = threadIdx.x;
  int wave = tid >> 6, lane = tid & 63;
  int wr = wave >> 1, wc = wave & 1;
  int la = lane & 15, ks = lane >> 4;

  int rIn = tid >> 3;
  int csrc = ((tid & 7) << 4) ^ ((rIn & 7) << 4);
  const char *srcA[4], *srcB[4];
  #pragma unroll
  for (int j = 0; j < 4; j++) {
    int row = j * 32 + rIn;
    srcA[j] = (const char*)A + (size_t)row * KD * 2 + csrc;
    srcB[j] = (const char*)B + (size_t)row * KD * 2 + csrc;
  }

  int offA[4][2], offB[4][2];
  #pragma unroll
  for (int m = 0; m < 4; m++) {
    int arow = wr * 64 + m * 16 + la;
    int brow = wc * 64 + m * 16 + la;
    #pragma unroll
    for (int kk = 0; kk < 2; kk++) {
      int c = kk * 64 + ks * 16;
      offA[m][kk] = arow * 128 + (c ^ ((arow & 7) << 4));
      offB[m][kk] = brow * 128 + (c ^ ((brow & 7) << 4));
    }
  }

  f32x4 zero4 = {0.f, 0.f, 0.f, 0.f};
  f32x4 acc[4][4];
  #pragma unroll
  for (int m = 0; m < 4; m++)
    #pragma unroll
    for (int n = 0; n < 4; n++) acc[m][n] = zero4;

  auto STAGE = [&](int p, int k0) {
    char* b = lds[p];
    #pragma unroll
    for (int j = 0; j < 4; j++)
      gload16(srcA[j] + k0, b + j * 4096 + wave * 1024);
    #pragma unroll
    for (int j = 0; j < 4; j++)
      gload16(srcB[j] + k0, b + 16384 + j * 4096 + wave * 1024);
  };

  STAGE(0, 0);
  STAGE(1, 128);
  asm volatile("s_waitcnt vmcnt(8)" ::: "memory");
  __builtin_amdgcn_sched_barrier(0);
  __builtin_amdgcn_s_barrier();

  for (int t = 0; t < NT; ++t) {
    int p = t & 1;
    const char* Ab = lds[p];
    const char* Bb = lds[p] + 16384;
    s16x8 a0[4], b0[4], a1[4], b1[4];
    #pragma unroll
    for (int m = 0; m < 4; m++) a0[m] = *(const s16x8*)(Ab + offA[m][0]);
    #pragma unroll
    for (int n = 0; n < 4; n++) b0[n] = *(const s16x8*)(Bb + offB[n][0]);
    #pragma unroll
    for (int m = 0; m < 4; m++) a1[m] = *(const s16x8*)(Ab + offA[m][1]);
    #pragma unroll
    for (int n = 0; n < 4; n++) b1[n] = *(const s16x8*)(Bb + offB[n][1]);
    asm volatile("s_waitcnt lgkmcnt(8)" ::: "memory");  // first-half frags landed
    __builtin_amdgcn_sched_barrier(0);
    __builtin_amdgcn_s_setprio(1);
    #pragma unroll
    for (int m = 0; m < 4; m++)
      #pragma unroll
      for (int n = 0; n < 4; n++) acc[m][n] = mfma16(a0[m], b0[n], acc[m][n]);
    __builtin_amdgcn_s_setprio(0);
    asm volatile("s_waitcnt lgkmcnt(0)" ::: "memory");
    __builtin_amdgcn_sched_barrier(0);
    __builtin_amdgcn_s_barrier();
    if (t + 2 < NT) STAGE(p, (t + 2) * 128);
    __builtin_amdgcn_sched_barrier(0);
    __builtin_amdgcn_s_setprio(1);
    #pragma unroll
    for (int m = 0; m < 4; m++)
      #pragma unroll
      for (int n = 0; n < 4; n++) acc[m][n] = mfma16(a1[m], b1[n], acc[m][n]);
    __builtin_amdgcn_s_setprio(0);
    if (t + 2 < NT) { asm volatile("s_waitcnt vmcnt(8)" ::: "memory"); }
    else            { asm volatile("s_waitcnt vmcnt(0)" ::: "memory"); }
    __builtin_amdgcn_sched_barrier(0);
    __builtin_amdgcn_s_barrier();
  }

  #pragma unroll
  for (int m = 0; m < 4; m++) {
    #pragma unroll
    for (int r = 0; r < 4; r++) {
      int lr = wr * 64 + m * 16 + ks * 4 + r;
      if (routed) {
        if (bx * 128 + lr < cnt) {
          int si = rowBase + lr;
          float wv = wgt[si];
          #pragma unroll
          for (int n = 0; n < 4; n++) {
            int col = by * 128 + wc * 64 + n * 16 + la;
            rdown[(size_t)si * H + col] = f2bf(wv * acc[m][n][r]);
          }
        }
      } else {
        #pragma unroll
        for (int n = 0; n < 4; n++) {
          int col = by * 128 + wc * 64 + n * 16 + la;
          y[(size_t)(rowBase + lr) * H + col] = acc[m][n][r];
        }
      }
    }
  }
}

// ---------------- combine: y[tok] += rdown[slot0] + rdown[slot1] ----------------
__global__ __launch_bounds__(256) void k_combine(float* __restrict__ y,
                                                 const u16* __restrict__ rdown,
                                                 const int* __restrict__ slotmap) {
  int n = blockIdx.x;
  int s0 = slotmap[n * 2], s1 = slotmap[n * 2 + 1];
  const s16x8* r0 = (const s16x8*)(rdown + (size_t)s0 * H);
  const s16x8* r1 = (const s16x8*)(rdown + (size_t)s1 * H);
  f32x4* yp = (f32x4*)(y + (size_t)n * H);
  int t = threadIdx.x;
  s16x8 a = r0[t], b = r1[t];
  f32x4 y0 = yp[2 * t], y1 = yp[2 * t + 1];
  #pragma unroll
  for (int j = 0; j < 4; j++) {
    y0[j] += bf2f((u16)a[j]) + bf2f((u16)b[j]);
    y1[j] += bf2f((u16)a[4 + j]) + bf2f((u16)b[4 + j]);
  }
  yp[2 * t] = y0;
  yp[2 * t + 1] = y1;
}

// ---------------- host launch ----------------

extern "C" void kernel_launch(void* const* d_in, const int* in_sizes, int n_in,
                              void* d_out, int out_size, void* d_ws, size_t ws_size,
                              hipStream_t stream) {
  const float* x   = (const float*)d_in[0];
  const float* gw  = (const float*)d_in[1];
  const float* Wg  = (const float*)d_in[2];
  const float* Wu  = (const float*)d_in[3];
  const float* Wd  = (const float*)d_in[4];
  const float* sWg = (const float*)d_in[5];
  const float* sWu = (const float*)d_in[6];
  const float* sWd = (const float*)d_in[7];
  float* y = (float*)d_out;

  char* w = (char*)d_ws;
  auto alloc = [&](size_t bytes) {
    char* p = w;
    w += (bytes + 255) & ~(size_t)255;
    return p;
  };
  u16* xbf   = (u16*)alloc((size_t)NTOK * H * 2);
  u16* WgT   = (u16*)alloc((size_t)NE * MDIM * H * 2);
  u16* WuT   = (u16*)alloc((size_t)NE * MDIM * H * 2);
  u16* WdT   = (u16*)alloc((size_t)NE * H * MDIM * 2);
  u16* sWgT  = (u16*)alloc((size_t)MS * H * 2);
  u16* sWuT  = (u16*)alloc((size_t)MS * H * 2);
  u16* sWdT  = (u16*)alloc((size_t)H * MS * 2);
  u16* act_s = (u16*)alloc((size_t)NTOK * MS * 2);
  u16* act_r = (u16*)alloc((size_t)ACT_R_ROWS * MDIM * 2);
  u16* rdown = (u16*)alloc((size_t)ACT_R_ROWS * H * 2);
  int*   te      = (int*)alloc((size_t)NTOK * 2 * 4);
  float* tw      = (float*)alloc((size_t)NTOK * 2 * 4);
  int*   counts  = (int*)alloc(64);
  int*   offs    = (int*)alloc(64);
  int*   perm    = (int*)alloc((size_t)ACT_R_ROWS * 4);
  float* wgt     = (float*)alloc((size_t)ACT_R_ROWS * 4);
  int*   slotmap = (int*)alloc((size_t)NTOK * 2 * 4);

  // merged front: xlog (512 blocks) + all weight transposes (7680 blocks)
  k_front<<<NTOK / 4 + 7680, 256, 0, stream>>>(
      x, gw, xbf, te, tw, Wg, Wu, Wd, sWg, sWu, sWd,
      WgT, WuT, WdT, sWgT, sWuT, sWdT);

  // deterministic dispatch build
  k_build<<<1, 256, 0, stream>>>(te, tw, counts, offs, perm, wgt, slotmap);

  // merged shared + routed gate/up, fused SwiGLU, counted-vmcnt pipeline (r9)
  k_gu<<<80 * 16, 256, 0, stream>>>(
      xbf, WgT, WuT, sWgT, sWuT, act_s, act_r, perm, counts, offs);

  // merged down: 128-col tiles; shared -> dense y; routed -> weighted bf16 rdown
  k_down2<<<8 * 18 * 16, 256, 0, stream>>>(
      act_s, act_r, sWdT, WdT, y, rdown, wgt, counts, offs);

  // per-token combine of the two routed contributions
  k_combine<<<NTOK, 256, 0, stream>>>(y, rdown, slotmap);
}